// Round 1
// baseline (972.370 us; speedup 1.0000x reference)
//
#include <hip/hip_runtime.h>
#include <stdint.h>

#define B_DIM 8192
#define K_DIM 4096   // in_dim
#define N_DIM 4096   // out_dim

typedef unsigned short u16;
typedef float f4 __attribute__((ext_vector_type(4)));
typedef float f32x4 __attribute__((ext_vector_type(4)));
typedef __bf16 bf16x8 __attribute__((ext_vector_type(8)));
typedef unsigned short u16x8 __attribute__((ext_vector_type(8)));
typedef unsigned short u16x4 __attribute__((ext_vector_type(4)));

#define AS1(p) ((const __attribute__((address_space(1))) void*)(p))
#define AS3(p) ((__attribute__((address_space(3))) void*)(p))

__device__ __forceinline__ u16 f2bf(float f) {
  uint32_t u = __builtin_bit_cast(uint32_t, f);
  u += 0x7fffu + ((u >> 16) & 1u);   // RNE
  return (u16)(u >> 16);
}

__device__ __forceinline__ float wred(float v) {
#pragma unroll
  for (int o = 32; o > 0; o >>= 1) v += __shfl_xor(v, o);
  return v;
}

// ---------------- init: zero atomic accumulators ----------------
__global__ void k_init(float* __restrict__ stats) {
  for (int i = threadIdx.x; i < 8194; i += 256) stats[i] = 0.0f;
}

// ---------------- Wsum = bf16(W_slow + W_fast) ----------------
__global__ __launch_bounds__(256) void k_prep_w(const f4* __restrict__ wslow, const f4* __restrict__ wfast,
                                                u16x4* __restrict__ wo) {
  size_t stride = (size_t)gridDim.x * 256;
  size_t n4 = (size_t)N_DIM * K_DIM / 4;
  for (size_t i = (size_t)blockIdx.x * 256 + threadIdx.x; i < n4; i += stride) {
    f4 a = wslow[i], b = wfast[i];
    u16x4 o;
#pragma unroll
    for (int j = 0; j < 4; ++j) o[j] = f2bf(a[j] + b[j]);
    wo[i] = o;
  }
}

// ---------------- x -> bf16, accumulate sum(x^2) ----------------
__global__ __launch_bounds__(256) void k_prep_x(const f4* __restrict__ x, u16x4* __restrict__ xb,
                                                float* __restrict__ xsumsq) {
  __shared__ float red[4];
  size_t stride = (size_t)gridDim.x * 256;
  size_t n4 = (size_t)B_DIM * K_DIM / 4;
  float s = 0.f;
  for (size_t i = (size_t)blockIdx.x * 256 + threadIdx.x; i < n4; i += stride) {
    f4 v = x[i];
    u16x4 o;
#pragma unroll
    for (int j = 0; j < 4; ++j) { o[j] = f2bf(v[j]); s += v[j] * v[j]; }
    xb[i] = o;
  }
  s = wred(s);
  int lane = threadIdx.x & 63, wave = threadIdx.x >> 6;
  if (lane == 0) red[wave] = s;
  __syncthreads();
  if (threadIdx.x == 0) atomicAdd(xsumsq, red[0] + red[1] + red[2] + red[3]);
}

// ---------------- bt-GEMM: C[M][N] = A[M][K] * B[N][K]^T (bf16 in, f32 out) ----------------
// 128x128 tile, BK=32, 4 waves (2x2), 64x64 per wave, 16x16x32 MFMA, global_load_lds w=16.
__global__ __launch_bounds__(256) void gemm_bt(const u16* __restrict__ A, const u16* __restrict__ Bm,
                                               float* __restrict__ C, int M, int N, int K) {
  __shared__ __align__(16) u16 As[128 * 32];
  __shared__ __align__(16) u16 Bs[128 * 32];
  int tid = threadIdx.x, wave = tid >> 6, lane = tid & 63;
  int m0 = blockIdx.y * 128, n0 = blockIdx.x * 128;
  int wr = (wave >> 1) * 64, wc = (wave & 1) * 64;
  int lr = lane & 15, lk = (lane >> 4) * 8;
  int srow_lane = lane >> 2;          // 0..15 within 16-row group
  int scol = (lane & 3) * 8;          // element offset within row (8 bf16 = 16B)

  f32x4 acc[4][4] = {};

  for (int kt = 0; kt < K; kt += 32) {
    __syncthreads();
#pragma unroll
    for (int q = 0; q < 2; ++q) {
      int rbase = wave * 32 + q * 16;
      int r = rbase + srow_lane;
      __builtin_amdgcn_global_load_lds(AS1(A + (size_t)(m0 + r) * K + kt + scol),
                                       AS3(&As[rbase * 32]), 16, 0, 0);
      __builtin_amdgcn_global_load_lds(AS1(Bm + (size_t)(n0 + r) * K + kt + scol),
                                       AS3(&Bs[rbase * 32]), 16, 0, 0);
    }
    __syncthreads();
    bf16x8 af[4], bfr[4];
#pragma unroll
    for (int m = 0; m < 4; ++m) af[m] = *(const bf16x8*)&As[(wr + m * 16 + lr) * 32 + lk];
#pragma unroll
    for (int n = 0; n < 4; ++n) bfr[n] = *(const bf16x8*)&Bs[(wc + n * 16 + lr) * 32 + lk];
#pragma unroll
    for (int m = 0; m < 4; ++m)
#pragma unroll
      for (int n = 0; n < 4; ++n)
        acc[m][n] = __builtin_amdgcn_mfma_f32_16x16x32_bf16(af[m], bfr[n], acc[m][n], 0, 0, 0);
  }

  int orow = (lane >> 4) * 4;   // C/D: col = lane&15, row = (lane>>4)*4 + j   [m89-verified]
  int ocol = lane & 15;
#pragma unroll
  for (int m = 0; m < 4; ++m)
#pragma unroll
    for (int n = 0; n < 4; ++n)
#pragma unroll
      for (int j = 0; j < 4; ++j)
        C[(size_t)(m0 + wr + m * 16 + orow + j) * N + (n0 + wc + n * 16 + ocol)] = acc[m][n][j];
}

// ---------------- column stats over batch ----------------
__global__ __launch_bounds__(256) void k_colstats(const float* __restrict__ pre,
                                                  float* __restrict__ colsum, float* __restrict__ colsumsq) {
  int col = blockIdx.x * 256 + threadIdx.x;
  int r0 = blockIdx.y * 128;
  const float* p = pre + (size_t)r0 * N_DIM + col;
  float s = 0.f, q = 0.f;
#pragma unroll 4
  for (int i = 0; i < 128; ++i) {
    float v = p[(size_t)i * N_DIM];
    s += v; q += v * v;
  }
  atomicAdd(&colsum[col], s);
  atomicAdd(&colsumsq[col], q);
}

// ---------------- plasticity MLP per column ----------------
__global__ __launch_bounds__(256) void k_mlp(const float* __restrict__ colsum, const float* __restrict__ colsumsq,
                                             const float* __restrict__ w1, const float* __restrict__ b1,
                                             const float* __restrict__ w2, const float* __restrict__ b2,
                                             const float* __restrict__ gp, float* __restrict__ eff,
                                             float* __restrict__ effsum) {
  __shared__ float red[4];
  int c = blockIdx.x * 256 + threadIdx.x;
  float mean = colsum[c] * (1.0f / B_DIM);
  float var = (colsumsq[c] - (float)B_DIM * mean * mean) * (1.0f / (B_DIM - 1));
  float sd = sqrtf(fmaxf(var, 0.f)) + 1e-6f;
  float acc = b2[0];
#pragma unroll
  for (int i = 0; i < 16; ++i) {
    float h = tanhf(mean * w1[2 * i] + sd * w1[2 * i + 1] + b1[i]);
    acc += h * w2[i];
  }
  float p = 1.0f / (1.0f + expf(-acc));
  float e = gp[0] * p;          // * (1 - PRED_ERR), PRED_ERR = 0
  eff[c] = e;
  float s = wred(e);
  int lane = threadIdx.x & 63, wave = threadIdx.x >> 6;
  if (lane == 0) red[wave] = s;
  __syncthreads();
  if (threadIdx.x == 0) atomicAdd(effsum, red[0] + red[1] + red[2] + red[3]);
}

// ---------------- row LayerNorm + 5*tanh(/5); in-place over pre_act; also bf16 copy ----------------
__global__ __launch_bounds__(256) void k_ln(const float* __restrict__ pre, const float* __restrict__ gamma,
                                            const float* __restrict__ beta, float* __restrict__ outF,
                                            u16* __restrict__ outB) {
  __shared__ float row[N_DIM];
  __shared__ float red[2][4];
  int t = threadIdx.x, lane = t & 63, wave = t >> 6;
  const float* p = pre + (size_t)blockIdx.x * N_DIM;
  float s = 0.f;
#pragma unroll
  for (int q = 0; q < 4; ++q) {
    int c = (q * 256 + t) * 4;
    f4 v = *(const f4*)&p[c];
    *(f4*)&row[c] = v;
    s += v[0] + v[1] + v[2] + v[3];
  }
  s = wred(s);
  if (lane == 0) red[0][wave] = s;
  __syncthreads();
  float mean = (red[0][0] + red[0][1] + red[0][2] + red[0][3]) * (1.0f / N_DIM);
  float vs = 0.f;
#pragma unroll
  for (int q = 0; q < 4; ++q) {
    int c = (q * 256 + t) * 4;
    f4 v = *(const f4*)&row[c];
#pragma unroll
    for (int j = 0; j < 4; ++j) { float d = v[j] - mean; vs += d * d; }
  }
  vs = wred(vs);
  if (lane == 0) red[1][wave] = vs;
  __syncthreads();
  float var = (red[1][0] + red[1][1] + red[1][2] + red[1][3]) * (1.0f / N_DIM);
  float rstd = rsqrtf(var + 1e-5f);
  float* o = outF + (size_t)blockIdx.x * N_DIM;
  u16* ob = outB + (size_t)blockIdx.x * N_DIM;
#pragma unroll
  for (int q = 0; q < 4; ++q) {
    int c = (q * 256 + t) * 4;
    f4 v = *(const f4*)&row[c];
    f4 g = *(const f4*)&gamma[c];
    f4 be = *(const f4*)&beta[c];
    f4 r;
    u16x4 rb;
#pragma unroll
    for (int j = 0; j < 4; ++j) {
      float ln = (v[j] - mean) * rstd * g[j] + be[j];
      float ov = 5.0f * tanhf(ln * 0.2f);
      r[j] = ov; rb[j] = f2bf(ov);
    }
    *(f4*)&o[c] = r;
    *(u16x4*)&ob[c] = rb;
  }
}

// ---------------- bf16 64x64 tile transpose: dst[c][r] = src[r][c] ----------------
__global__ __launch_bounds__(256) void k_transpose(const u16* __restrict__ src, u16* __restrict__ dst,
                                                   int R, int C) {
  __shared__ u16 tile[64][65];
  int tc = blockIdx.x, tr = blockIdx.y;
  int t = threadIdx.x;
#pragma unroll
  for (int q = 0; q < 2; ++q) {
    int idx = q * 256 + t;
    int row = idx >> 3, cg = idx & 7;
    u16x8 v = *(const u16x8*)&src[(size_t)(tr * 64 + row) * C + tc * 64 + cg * 8];
#pragma unroll
    for (int j = 0; j < 8; ++j) tile[row][cg * 8 + j] = v[j];
  }
  __syncthreads();
#pragma unroll
  for (int q = 0; q < 2; ++q) {
    int idx = q * 256 + t;
    int row = idx >> 3, cg = idx & 7;
    u16x8 v;
#pragma unroll
    for (int j = 0; j < 8; ++j) v[j] = tile[cg * 8 + j][row];
    *(u16x8*)&dst[(size_t)(tc * 64 + row) * R + tr * 64 + cg * 8] = v;
  }
}

// ---------------- Hebbian W_fast update (in-place over corr region of d_out) ----------------
__global__ __launch_bounds__(256) void k_update(const float* __restrict__ corr, const float* __restrict__ wf,
                                                const float* __restrict__ eff, const float* __restrict__ sc,
                                                float* __restrict__ out_wf) {
  // sc[0] = sum(x^2) over all elements, sc[1] = sum(eff)
  float xn = sc[0] * (1.0f / B_DIM) + 1e-6f;
  float inv = 1.0f / ((float)B_DIM * xn);          // corr_raw -> correlation/x_norm
  bool on = (sc[1] * (1.0f / N_DIM)) > 0.001f;
  size_t i = ((size_t)blockIdx.x * 256 + threadIdx.x) * 4;
  int n = (int)(i >> 12);                          // / K_DIM
  float lr = eff[n] * 0.015f;
  f4 c4 = *(const f4*)&corr[i];
  f4 w4 = *(const f4*)&wf[i];
  f4 r;
#pragma unroll
  for (int j = 0; j < 4; ++j) {
    float delta = fminf(fmaxf(c4[j] * inv - 0.2f * w4[j], -0.05f), 0.05f);
    r[j] = on ? (w4[j] + delta * lr) * 0.999f : w4[j];
  }
  *(f4*)&out_wf[i] = r;
}

extern "C" void kernel_launch(void* const* d_in, const int* in_sizes, int n_in,
                              void* d_out, int out_size, void* d_ws, size_t ws_size,
                              hipStream_t stream) {
  const float* x      = (const float*)d_in[0];
  const float* W_slow = (const float*)d_in[1];
  const float* W_fast = (const float*)d_in[2];
  const float* gamma  = (const float*)d_in[3];
  const float* beta   = (const float*)d_in[4];
  const float* w1     = (const float*)d_in[5];
  const float* b1     = (const float*)d_in[6];
  const float* w2     = (const float*)d_in[7];
  const float* b2     = (const float*)d_in[8];
  const float* gp     = (const float*)d_in[9];

  float* outF = (float*)d_out;                         // [8192][4096] out
  float* outW = (float*)d_out + (size_t)B_DIM * N_DIM; // [4096][4096] new_W_fast
  // pre_act lives in outF region (overwritten in-place by LN); corr lives in outW region.

  uint8_t* ws = (uint8_t*)d_ws;
  u16*  x_bf   = (u16*)(ws + 0);                        // 64MB, [0,67108864)
  u16*  outT   = (u16*)(ws + 0);                        // alias after x-transpose
  u16*  wsum   = (u16*)(ws + 67108864);                 // 32MB
  u16*  out_bf = (u16*)(ws + 67108864);                 // alias after GEMM1 (64MB)
  u16*  xT     = (u16*)(ws + 134217728);                // 64MB
  float* stats = (float*)(ws + 201326592);
  float* colsum   = stats;          // 4096
  float* colsumsq = stats + 4096;   // 4096
  float* xsumsq   = stats + 8192;   // 1
  float* effsum   = stats + 8193;   // 1
  float* eff      = stats + 8448;   // 4096

  k_init<<<1, 256, 0, stream>>>(stats);
  k_prep_w<<<2048, 256, 0, stream>>>((const f4*)W_slow, (const f4*)W_fast, (u16x4*)wsum);
  k_prep_x<<<2048, 256, 0, stream>>>((const f4*)x, (u16x4*)x_bf, xsumsq);
  gemm_bt<<<dim3(N_DIM / 128, B_DIM / 128), 256, 0, stream>>>(x_bf, wsum, outF, B_DIM, N_DIM, K_DIM);
  k_colstats<<<dim3(N_DIM / 256, B_DIM / 128), 256, 0, stream>>>(outF, colsum, colsumsq);
  k_mlp<<<N_DIM / 256, 256, 0, stream>>>(colsum, colsumsq, w1, b1, w2, b2, gp, eff, effsum);
  k_ln<<<B_DIM, 256, 0, stream>>>(outF, gamma, beta, outF, out_bf);
  k_transpose<<<dim3(K_DIM / 64, B_DIM / 64), 256, 0, stream>>>(x_bf, xT, B_DIM, K_DIM);
  k_transpose<<<dim3(N_DIM / 64, B_DIM / 64), 256, 0, stream>>>(out_bf, outT, B_DIM, N_DIM);
  gemm_bt<<<dim3(K_DIM / 128, N_DIM / 128), 256, 0, stream>>>(outT, xT, outW, N_DIM, K_DIM, B_DIM);
  k_update<<<(N_DIM * K_DIM / 4) / 256, 256, 0, stream>>>(outW, W_fast, eff, xsumsq, outW);
}

// Round 2
// 739.765 us; speedup vs baseline: 1.3144x; 1.3144x over previous
//
#include <hip/hip_runtime.h>
#include <stdint.h>

#define B_DIM 8192
#define K_DIM 4096   // in_dim
#define N_DIM 4096   // out_dim

typedef unsigned short u16;
typedef float f4 __attribute__((ext_vector_type(4)));
typedef float f32x4 __attribute__((ext_vector_type(4)));
typedef __bf16 bf16x8 __attribute__((ext_vector_type(8)));
typedef unsigned short u16x8 __attribute__((ext_vector_type(8)));
typedef unsigned short u16x4 __attribute__((ext_vector_type(4)));

#define AS1(p) ((const __attribute__((address_space(1))) void*)(p))
#define AS3(p) ((__attribute__((address_space(3))) void*)(p))

__device__ __forceinline__ u16 f2bf(float f) {
  uint32_t u = __builtin_bit_cast(uint32_t, f);
  u += 0x7fffu + ((u >> 16) & 1u);   // RNE
  return (u16)(u >> 16);
}

__device__ __forceinline__ float wred(float v) {
#pragma unroll
  for (int o = 32; o > 0; o >>= 1) v += __shfl_xor(v, o);
  return v;
}

// ---------------- init: zero atomic accumulators ----------------
__global__ void k_init(float* __restrict__ stats) {
  for (int i = threadIdx.x; i < 8194; i += 256) stats[i] = 0.0f;
}

// ---------------- Wsum = bf16(W_slow + W_fast) ----------------
__global__ __launch_bounds__(256) void k_prep_w(const f4* __restrict__ wslow, const f4* __restrict__ wfast,
                                                u16x4* __restrict__ wo) {
  size_t stride = (size_t)gridDim.x * 256;
  size_t n4 = (size_t)N_DIM * K_DIM / 4;
  for (size_t i = (size_t)blockIdx.x * 256 + threadIdx.x; i < n4; i += stride) {
    f4 a = wslow[i], b = wfast[i];
    u16x4 o;
#pragma unroll
    for (int j = 0; j < 4; ++j) o[j] = f2bf(a[j] + b[j]);
    wo[i] = o;
  }
}

// ---------------- x -> bf16, accumulate sum(x^2) ----------------
__global__ __launch_bounds__(256) void k_prep_x(const f4* __restrict__ x, u16x4* __restrict__ xb,
                                                float* __restrict__ xsumsq) {
  __shared__ float red[4];
  size_t stride = (size_t)gridDim.x * 256;
  size_t n4 = (size_t)B_DIM * K_DIM / 4;
  float s = 0.f;
  for (size_t i = (size_t)blockIdx.x * 256 + threadIdx.x; i < n4; i += stride) {
    f4 v = x[i];
    u16x4 o;
#pragma unroll
    for (int j = 0; j < 4; ++j) { o[j] = f2bf(v[j]); s += v[j] * v[j]; }
    xb[i] = o;
  }
  s = wred(s);
  int lane = threadIdx.x & 63, wave = threadIdx.x >> 6;
  if (lane == 0) red[wave] = s;
  __syncthreads();
  if (threadIdx.x == 0) atomicAdd(xsumsq, red[0] + red[1] + red[2] + red[3]);
}

// ============ 256x256-tile 8-phase bt-GEMM: C[M][N] = A[M][K] * B[N][K]^T ============
// bf16 in, f32 out. BK=64, 512 threads = 8 waves (2M x 4N), wave tile 128x64.
// LDS 128KB double-buffered; XOR-swizzle (row&7 -> byte bits[6:4]) applied via
// pre-swizzled global source (global_load_lds writes linearly) + swizzled ds_read.
// Counted vmcnt(6) per K-tile (3 half-tiles in flight); setprio around MFMA clusters.
__global__ __launch_bounds__(512, 2) void gemm8(const u16* __restrict__ A, const u16* __restrict__ Bm,
                                                float* __restrict__ C, int M, int N, int K) {
  __shared__ __align__(16) u16 As[32768];   // 2 bufs x 256 rows x 64 cols
  __shared__ __align__(16) u16 Bs[32768];

  const int tid = threadIdx.x, wave = tid >> 6, lane = tid & 63;
  const int li = lane & 15, hi = lane >> 4;
  const int wm = wave >> 2, wn = wave & 3;

  // bijective XCD swizzle (grid % 8 == 0 for both call sites)
  const int GX = N >> 8;
  const int nwg = GX * (M >> 8);
  int bid = blockIdx.y * GX + blockIdx.x;
  int swz = (bid & 7) * (nwg >> 3) + (bid >> 3);
  const int bx = swz % GX, by = swz / GX;
  const int m0 = by * 256, n0 = bx * 256;

  // per-lane staging source offsets (elements), swizzle-inverted:
  // LDS linear byte O holds tile byte T = O ^ (((O>>7)&7)<<4)
  int srcoff[2][2];
#pragma unroll
  for (int h = 0; h < 2; ++h)
#pragma unroll
    for (int q = 0; q < 2; ++q) {
      int O = h * 16384 + q * 8192 + wave * 1024 + lane * 16;
      int T = O ^ (((O >> 7) & 7) << 4);
      srcoff[h][q] = (T >> 7) * K + ((T & 127) >> 1);
    }

  const u16* Abase = A + (size_t)m0 * K;
  const u16* Bbase = Bm + (size_t)n0 * K;

#define STG_A(buf, h, kt) do { \
  __builtin_amdgcn_global_load_lds(AS1(Abase + (kt) + srcoff[h][0]), AS3(&As[(buf)*16384 + (h)*8192 + wave*512]), 16, 0, 0); \
  __builtin_amdgcn_global_load_lds(AS1(Abase + (kt) + srcoff[h][1]), AS3(&As[(buf)*16384 + (h)*8192 + 4096 + wave*512]), 16, 0, 0); \
} while (0)
#define STG_B(buf, h, kt) do { \
  __builtin_amdgcn_global_load_lds(AS1(Bbase + (kt) + srcoff[h][0]), AS3(&Bs[(buf)*16384 + (h)*8192 + wave*512]), 16, 0, 0); \
  __builtin_amdgcn_global_load_lds(AS1(Bbase + (kt) + srcoff[h][1]), AS3(&Bs[(buf)*16384 + (h)*8192 + 4096 + wave*512]), 16, 0, 0); \
} while (0)

  const int xa = (li & 7) << 3;                       // element-index XOR (byte bits[6:4])
  const int abase = (wm * 128 + li) * 64 + hi * 8;
  const int bbase = (wn * 64 + li) * 64 + hi * 8;
#define LDA_(dst, buf, m, ks) dst = *(const bf16x8*)&As[(buf)*16384 + (((abase + (m)*1024 + (ks)*32)) ^ xa)]
#define LDB_(dst, buf, n, ks) dst = *(const bf16x8*)&Bs[(buf)*16384 + (((bbase + (n)*1024 + (ks)*32)) ^ xa)]

  f32x4 acc[8][4] = {};
  bf16x8 a[8][2], b[4][2];
  const int NT = K >> 6;

  // prologue: tile0 {A0,A1,B0,B1} -> buf0 ; tile1 {A0,A1,B0} -> buf1
  STG_A(0, 0, 0); STG_A(0, 1, 0); STG_B(0, 0, 0); STG_B(0, 1, 0);
  STG_A(1, 0, 64); STG_A(1, 1, 64); STG_B(1, 0, 64);
  asm volatile("s_waitcnt vmcnt(6)" ::: "memory");
  __builtin_amdgcn_s_barrier();

  for (int t = 0; t < NT; ++t) {
    const int buf = t & 1;
    const int ktn = (t + 1) << 6, ktnn = (t + 2) << 6;

    // ---- P0: read a[0..3], b[0..1]; stage B1(t+1) -> buf^1 ----
#pragma unroll
    for (int m = 0; m < 4; ++m) { LDA_(a[m][0], buf, m, 0); LDA_(a[m][1], buf, m, 1); }
#pragma unroll
    for (int n = 0; n < 2; ++n) { LDB_(b[n][0], buf, n, 0); LDB_(b[n][1], buf, n, 1); }
    if (t + 1 < NT) STG_B(buf ^ 1, 1, ktn);
    __builtin_amdgcn_s_barrier();
    asm volatile("s_waitcnt lgkmcnt(0)" ::: "memory");
    __builtin_amdgcn_sched_barrier(0);
    __builtin_amdgcn_s_setprio(1);
#pragma unroll
    for (int ks = 0; ks < 2; ++ks)
#pragma unroll
      for (int m = 0; m < 4; ++m)
#pragma unroll
        for (int n = 0; n < 2; ++n)
          acc[m][n] = __builtin_amdgcn_mfma_f32_16x16x32_bf16(a[m][ks], b[n][ks], acc[m][n], 0, 0, 0);
    __builtin_amdgcn_s_setprio(0);
    __builtin_amdgcn_s_barrier();

    // ---- P1: read a[4..7] ----
#pragma unroll
    for (int m = 4; m < 8; ++m) { LDA_(a[m][0], buf, m, 0); LDA_(a[m][1], buf, m, 1); }
    __builtin_amdgcn_s_barrier();
    asm volatile("s_waitcnt lgkmcnt(0)" ::: "memory");
    __builtin_amdgcn_sched_barrier(0);
    __builtin_amdgcn_s_setprio(1);
#pragma unroll
    for (int ks = 0; ks < 2; ++ks)
#pragma unroll
      for (int m = 4; m < 8; ++m)
#pragma unroll
        for (int n = 0; n < 2; ++n)
          acc[m][n] = __builtin_amdgcn_mfma_f32_16x16x32_bf16(a[m][ks], b[n][ks], acc[m][n], 0, 0, 0);
    __builtin_amdgcn_s_setprio(0);
    __builtin_amdgcn_s_barrier();

    // ---- P2: read b[2..3]; stage A0,A1(t+2) -> buf (reads of A done @P1) ----
#pragma unroll
    for (int n = 2; n < 4; ++n) { LDB_(b[n][0], buf, n, 0); LDB_(b[n][1], buf, n, 1); }
    if (t + 2 < NT) { STG_A(buf, 0, ktnn); STG_A(buf, 1, ktnn); }
    __builtin_amdgcn_s_barrier();
    asm volatile("s_waitcnt lgkmcnt(0)" ::: "memory");
    __builtin_amdgcn_sched_barrier(0);
    __builtin_amdgcn_s_setprio(1);
#pragma unroll
    for (int ks = 0; ks < 2; ++ks)
#pragma unroll
      for (int m = 0; m < 4; ++m)
#pragma unroll
        for (int n = 2; n < 4; ++n)
          acc[m][n] = __builtin_amdgcn_mfma_f32_16x16x32_bf16(a[m][ks], b[n][ks], acc[m][n], 0, 0, 0);
    __builtin_amdgcn_s_setprio(0);
    __builtin_amdgcn_s_barrier();

    // ---- P3: stage B0(t+2) -> buf (reads of B-half0 done @P2); boundary vmcnt ----
    if (t + 2 < NT) STG_B(buf, 0, ktnn);
    __builtin_amdgcn_s_barrier();
    __builtin_amdgcn_s_setprio(1);
#pragma unroll
    for (int ks = 0; ks < 2; ++ks)
#pragma unroll
      for (int m = 4; m < 8; ++m)
#pragma unroll
        for (int n = 2; n < 4; ++n)
          acc[m][n] = __builtin_amdgcn_mfma_f32_16x16x32_bf16(a[m][ks], b[n][ks], acc[m][n], 0, 0, 0);
    __builtin_amdgcn_s_setprio(0);
    if (t + 1 < NT) {
      if (t + 2 < NT) asm volatile("s_waitcnt vmcnt(6)" ::: "memory");
      else            asm volatile("s_waitcnt vmcnt(0)" ::: "memory");
    }
    __builtin_amdgcn_s_barrier();
  }

  // epilogue: C/D layout col = lane&15, row = (lane>>4)*4 + j
  float* Cp = C + (size_t)(m0 + wm * 128 + hi * 4) * N + n0 + wn * 64 + li;
#pragma unroll
  for (int m = 0; m < 8; ++m)
#pragma unroll
    for (int n = 0; n < 4; ++n)
#pragma unroll
      for (int j = 0; j < 4; ++j)
        Cp[(size_t)(m * 16 + j) * N + n * 16] = acc[m][n][j];
#undef STG_A
#undef STG_B
#undef LDA_
#undef LDB_
}

// ---------------- column stats over batch ----------------
__global__ __launch_bounds__(256) void k_colstats(const float* __restrict__ pre,
                                                  float* __restrict__ colsum, float* __restrict__ colsumsq) {
  int col = blockIdx.x * 256 + threadIdx.x;
  int r0 = blockIdx.y * 128;
  const float* p = pre + (size_t)r0 * N_DIM + col;
  float s = 0.f, q = 0.f;
#pragma unroll 4
  for (int i = 0; i < 128; ++i) {
    float v = p[(size_t)i * N_DIM];
    s += v; q += v * v;
  }
  atomicAdd(&colsum[col], s);
  atomicAdd(&colsumsq[col], q);
}

// ---------------- plasticity MLP per column ----------------
__global__ __launch_bounds__(256) void k_mlp(const float* __restrict__ colsum, const float* __restrict__ colsumsq,
                                             const float* __restrict__ w1, const float* __restrict__ b1,
                                             const float* __restrict__ w2, const float* __restrict__ b2,
                                             const float* __restrict__ gp, float* __restrict__ eff,
                                             float* __restrict__ effsum) {
  __shared__ float red[4];
  int c = blockIdx.x * 256 + threadIdx.x;
  float mean = colsum[c] * (1.0f / B_DIM);
  float var = (colsumsq[c] - (float)B_DIM * mean * mean) * (1.0f / (B_DIM - 1));
  float sd = sqrtf(fmaxf(var, 0.f)) + 1e-6f;
  float acc = b2[0];
#pragma unroll
  for (int i = 0; i < 16; ++i) {
    float h = tanhf(mean * w1[2 * i] + sd * w1[2 * i + 1] + b1[i]);
    acc += h * w2[i];
  }
  float p = 1.0f / (1.0f + expf(-acc));
  float e = gp[0] * p;          // * (1 - PRED_ERR), PRED_ERR = 0
  eff[c] = e;
  float s = wred(e);
  int lane = threadIdx.x & 63, wave = threadIdx.x >> 6;
  if (lane == 0) red[wave] = s;
  __syncthreads();
  if (threadIdx.x == 0) atomicAdd(effsum, red[0] + red[1] + red[2] + red[3]);
}

// ---------------- row LayerNorm + 5*tanh(/5); in-place over pre_act; also bf16 copy ----------------
__global__ __launch_bounds__(256) void k_ln(const float* __restrict__ pre, const float* __restrict__ gamma,
                                            const float* __restrict__ beta, float* __restrict__ outF,
                                            u16* __restrict__ outB) {
  __shared__ float row[N_DIM];
  __shared__ float red[2][4];
  int t = threadIdx.x, lane = t & 63, wave = t >> 6;
  const float* p = pre + (size_t)blockIdx.x * N_DIM;
  float s = 0.f;
#pragma unroll
  for (int q = 0; q < 4; ++q) {
    int c = (q * 256 + t) * 4;
    f4 v = *(const f4*)&p[c];
    *(f4*)&row[c] = v;
    s += v[0] + v[1] + v[2] + v[3];
  }
  s = wred(s);
  if (lane == 0) red[0][wave] = s;
  __syncthreads();
  float mean = (red[0][0] + red[0][1] + red[0][2] + red[0][3]) * (1.0f / N_DIM);
  float vs = 0.f;
#pragma unroll
  for (int q = 0; q < 4; ++q) {
    int c = (q * 256 + t) * 4;
    f4 v = *(const f4*)&row[c];
#pragma unroll
    for (int j = 0; j < 4; ++j) { float d = v[j] - mean; vs += d * d; }
  }
  vs = wred(vs);
  if (lane == 0) red[1][wave] = vs;
  __syncthreads();
  float var = (red[1][0] + red[1][1] + red[1][2] + red[1][3]) * (1.0f / N_DIM);
  float rstd = rsqrtf(var + 1e-5f);
  float* o = outF + (size_t)blockIdx.x * N_DIM;
  u16* ob = outB + (size_t)blockIdx.x * N_DIM;
#pragma unroll
  for (int q = 0; q < 4; ++q) {
    int c = (q * 256 + t) * 4;
    f4 v = *(const f4*)&row[c];
    f4 g = *(const f4*)&gamma[c];
    f4 be = *(const f4*)&beta[c];
    f4 r;
    u16x4 rb;
#pragma unroll
    for (int j = 0; j < 4; ++j) {
      float ln = (v[j] - mean) * rstd * g[j] + be[j];
      float ov = 5.0f * tanhf(ln * 0.2f);
      r[j] = ov; rb[j] = f2bf(ov);
    }
    *(f4*)&o[c] = r;
    *(u16x4*)&ob[c] = rb;
  }
}

// ---------------- bf16 64x64 tile transpose: dst[c][r] = src[r][c] ----------------
__global__ __launch_bounds__(256) void k_transpose(const u16* __restrict__ src, u16* __restrict__ dst,
                                                   int R, int C) {
  __shared__ u16 tile[64][65];
  int tc = blockIdx.x, tr = blockIdx.y;
  int t = threadIdx.x;
#pragma unroll
  for (int q = 0; q < 2; ++q) {
    int idx = q * 256 + t;
    int row = idx >> 3, cg = idx & 7;
    u16x8 v = *(const u16x8*)&src[(size_t)(tr * 64 + row) * C + tc * 64 + cg * 8];
#pragma unroll
    for (int j = 0; j < 8; ++j) tile[row][cg * 8 + j] = v[j];
  }
  __syncthreads();
#pragma unroll
  for (int q = 0; q < 2; ++q) {
    int idx = q * 256 + t;
    int row = idx >> 3, cg = idx & 7;
    u16x8 v;
#pragma unroll
    for (int j = 0; j < 8; ++j) v[j] = tile[cg * 8 + j][row];
    *(u16x8*)&dst[(size_t)(tc * 64 + row) * R + tr * 64 + cg * 8] = v;
  }
}

// ---------------- Hebbian W_fast update (in-place over corr region of d_out) ----------------
__global__ __launch_bounds__(256) void k_update(const float* __restrict__ corr, const float* __restrict__ wf,
                                                const float* __restrict__ eff, const float* __restrict__ sc,
                                                float* __restrict__ out_wf) {
  float xn = sc[0] * (1.0f / B_DIM) + 1e-6f;
  float inv = 1.0f / ((float)B_DIM * xn);
  bool on = (sc[1] * (1.0f / N_DIM)) > 0.001f;
  size_t i = ((size_t)blockIdx.x * 256 + threadIdx.x) * 4;
  int n = (int)(i >> 12);
  float lr = eff[n] * 0.015f;
  f4 c4 = *(const f4*)&corr[i];
  f4 w4 = *(const f4*)&wf[i];
  f4 r;
#pragma unroll
  for (int j = 0; j < 4; ++j) {
    float delta = fminf(fmaxf(c4[j] * inv - 0.2f * w4[j], -0.05f), 0.05f);
    r[j] = on ? (w4[j] + delta * lr) * 0.999f : w4[j];
  }
  *(f4*)&out_wf[i] = r;
}

extern "C" void kernel_launch(void* const* d_in, const int* in_sizes, int n_in,
                              void* d_out, int out_size, void* d_ws, size_t ws_size,
                              hipStream_t stream) {
  const float* x      = (const float*)d_in[0];
  const float* W_slow = (const float*)d_in[1];
  const float* W_fast = (const float*)d_in[2];
  const float* gamma  = (const float*)d_in[3];
  const float* beta   = (const float*)d_in[4];
  const float* w1     = (const float*)d_in[5];
  const float* b1     = (const float*)d_in[6];
  const float* w2     = (const float*)d_in[7];
  const float* b2     = (const float*)d_in[8];
  const float* gp     = (const float*)d_in[9];

  float* outF = (float*)d_out;                         // [8192][4096] out
  float* outW = (float*)d_out + (size_t)B_DIM * N_DIM; // [4096][4096] new_W_fast

  uint8_t* ws = (uint8_t*)d_ws;
  u16*  x_bf   = (u16*)(ws + 0);                        // 64MB
  u16*  outT   = (u16*)(ws + 0);                        // alias after x-transpose
  u16*  wsum   = (u16*)(ws + 67108864);                 // 32MB
  u16*  out_bf = (u16*)(ws + 67108864);                 // alias after GEMM1 (64MB)
  u16*  xT     = (u16*)(ws + 134217728);                // 64MB
  float* stats = (float*)(ws + 201326592);
  float* colsum   = stats;
  float* colsumsq = stats + 4096;
  float* xsumsq   = stats + 8192;
  float* effsum   = stats + 8193;
  float* eff      = stats + 8448;

  k_init<<<1, 256, 0, stream>>>(stats);
  k_prep_w<<<2048, 256, 0, stream>>>((const f4*)W_slow, (const f4*)W_fast, (u16x4*)wsum);
  k_prep_x<<<2048, 256, 0, stream>>>((const f4*)x, (u16x4*)x_bf, xsumsq);
  gemm8<<<dim3(N_DIM / 256, B_DIM / 256), 512, 0, stream>>>(x_bf, wsum, outF, B_DIM, N_DIM, K_DIM);
  k_colstats<<<dim3(N_DIM / 256, B_DIM / 128), 256, 0, stream>>>(outF, colsum, colsumsq);
  k_mlp<<<N_DIM / 256, 256, 0, stream>>>(colsum, colsumsq, w1, b1, w2, b2, gp, eff, effsum);
  k_ln<<<B_DIM, 256, 0, stream>>>(outF, gamma, beta, outF, out_bf);
  k_transpose<<<dim3(K_DIM / 64, B_DIM / 64), 256, 0, stream>>>(x_bf, xT, B_DIM, K_DIM);
  k_transpose<<<dim3(N_DIM / 64, B_DIM / 64), 256, 0, stream>>>(out_bf, outT, B_DIM, N_DIM);
  gemm8<<<dim3(K_DIM / 256, N_DIM / 256), 512, 0, stream>>>(outT, xT, outW, N_DIM, K_DIM, B_DIM);
  k_update<<<(N_DIM * K_DIM / 4) / 256, 256, 0, stream>>>(outW, W_fast, eff, xsumsq, outW);
}